// Round 14
// baseline (837.383 us; speedup 1.0000x reference)
//
#include <hip/hip_runtime.h>
#include <hip/hip_bf16.h>
#include <hip/hip_cooperative_groups.h>

namespace cg = cooperative_groups;

// HeteroGraphEncoder: 3-layer hetero GraphSAGE + pool + MLP head.
// bf16 activations/weights (hi/lo compensated), fp32 accumulation.
// CSR build via LDS-privatized counting sort, now in ONE cooperative kernel.
// Layer 3 pool-before-GEMM; pool+tail in one cooperative kernel. 8 graph nodes.
// NE=1e5, NT=2e4, E=2e6, D=128, B=64, L=3.

#define D 128
#define NB 64
#define OUTD 64
#define NLAY 3
#define EPB 4096    // edges per block in bucket build
#define BSH2 9      // 512 dsts per bucket
#define PSPLIT 4    // sub-blocks per (source,batch) in pooling
#define CSRGRID 512
#define FINGRID 512

typedef __bf16 bf16;
typedef __bf16 bf16x4 __attribute__((ext_vector_type(4)));
typedef __bf16 bf16x8 __attribute__((ext_vector_type(8)));
typedef float  f32x16 __attribute__((ext_vector_type(16)));

#define LOAD16_TO_LDS(gp, lp) \
    __builtin_amdgcn_global_load_lds((const __attribute__((address_space(1))) void*)(gp), \
                                     (__attribute__((address_space(3))) void*)(lp), 16, 0, 0)

// ---------------- pool helper: stream contiguous rows of one source ----------------
__device__ __forceinline__ void pool_block_dev(const bf16* __restrict__ x, int s,
                                               const int* __restrict__ bounds, int b, int j,
                                               float* __restrict__ pooled5, float red[16][D]) {
    int start = bounds[b], end = bounds[b + 1];
    int len = end - start;
    if (len <= 0) return;
    int r0 = start + (int)(((long long)len * j) / PSPLIT);
    int r1 = start + (int)(((long long)len * (j + 1)) / PSPLIT);
    if (r0 >= r1) return;
    int slot = threadIdx.x >> 4;   // 0..15: row slot
    int ch   = threadIdx.x & 15;   // 16B col chunk
    float a[8] = {};
    for (int r = r0 + slot; r < r1; r += 16) {
        bf16x8 v = ((const bf16x8*)(x + (size_t)r * D))[ch];
        #pragma unroll
        for (int e = 0; e < 8; ++e) a[e] += (float)v[e];
    }
    #pragma unroll
    for (int e = 0; e < 8; ++e) red[slot][ch * 8 + e] = a[e];
    __syncthreads();
    int c = threadIdx.x;
    if (c < D) {
        float ssum = 0.f;
        #pragma unroll
        for (int k = 0; k < 16; ++k) ssum += red[k][c];
        atomicAdd(&pooled5[(size_t)s * NB * D + b * D + c], ssum);
    }
    __syncthreads();   // red[] reused across grid-stride iterations
}

// ================= front_all: gather + bounds + weight prep + bucket hist + zero ====
__global__ void front_all(const float* __restrict__ embE, const int* __restrict__ idsE,
                          bf16* __restrict__ xE, int nE,
                          const float* __restrict__ embT, const int* __restrict__ idsT,
                          bf16* __restrict__ xT, int nT,
                          const int* __restrict__ bEv, const int* __restrict__ bTr,
                          int* __restrict__ boundsE, int* __restrict__ boundsT,
                          const int* __restrict__ dEE, int nEE, int nbkEE, int nblkEE,
                          int* __restrict__ cntEE,
                          const int* __restrict__ dET, int nET, int nbkET, int nblkET,
                          int* __restrict__ cntET,
                          const int* __restrict__ dTE, int nTE, int nbkTE, int nblkTE,
                          int* __restrict__ cntTE,
                          const float* __restrict__ Wl, const float* __restrict__ Wr,
                          const float* __restrict__ bl,
                          bf16* __restrict__ wbuf, float* __restrict__ bbuf,
                          float* __restrict__ pooled5, int nGather) {
    __shared__ int h[256];
    int b = blockIdx.x;
    if (b < nGather) {
        int idx = b * 256 + threadIdx.x;
        const float* emb; const int* ids; bf16* x;
        int tE = nE * 32;
        if (idx < tE) { emb = embE; ids = idsE; x = xE; }
        else {
            idx -= tE;
            if (idx >= nT * 32) return;
            emb = embT; ids = idsT; x = xT;
        }
        int r = idx >> 5, v = idx & 31;
        float4 f = ((const float4*)(emb + (size_t)ids[r] * D))[v];
        bf16x4 o;
        o[0] = (bf16)f.x; o[1] = (bf16)f.y; o[2] = (bf16)f.z; o[3] = (bf16)f.w;
        ((bf16x4*)(x + (size_t)r * D))[v] = o;
        return;
    }
    b -= nGather;
    int nblkH = nblkEE + nblkET + nblkTE;
    if (b < nblkH) {
        const int* dst; int E, nbk, nblk, lb; int* cnt;
        if (b < nblkEE) { dst = dEE; E = nEE; nbk = nbkEE; nblk = nblkEE; cnt = cntEE; lb = b; }
        else if (b < nblkEE + nblkET) { dst = dET; E = nET; nbk = nbkET; nblk = nblkET; cnt = cntET; lb = b - nblkEE; }
        else { dst = dTE; E = nTE; nbk = nbkTE; nblk = nblkTE; cnt = cntTE; lb = b - nblkEE - nblkET; }
        h[threadIdx.x] = 0;
        __syncthreads();
        int e0 = lb * EPB, e1 = min(e0 + EPB, E);
        for (int e = e0 + threadIdx.x; e < e1; e += 256) atomicAdd(&h[dst[e] >> BSH2], 1);
        __syncthreads();
        for (int k = threadIdx.x; k < nbk; k += 256) cnt[k * nblk + lb] = h[k];
        return;
    }
    b -= nblkH;
    if (b < 120) {
        // weight prep: hi/lo split, packed in MFMA fragment order.
        // mat 0: Wl0  mat 1: Wl2  mat 2: Wr0+Wr2  mat 3: Wl1  mat 4: Wr1
        int idx = b * 256 + threadIdx.x;
        if (idx >= NLAY * 5 * 2048) return;
        int l = idx / (5 * 2048);
        int rem = idx - l * 5 * 2048;
        int mat = rem >> 11;
        int q = rem & 2047;
        int lane = q & 63, t = (q >> 6) & 7, w = q >> 9;
        int r = w * 32 + (lane & 31);
        int c = t * 16 + (lane >> 5) * 8;
        size_t l3 = (size_t)l * 3;
        const float* s0;
        const float* s1 = nullptr;
        switch (mat) {
            case 0: s0 = Wl + (l3 + 0) * D * D; break;
            case 1: s0 = Wl + (l3 + 2) * D * D; break;
            case 2: s0 = Wr + (l3 + 0) * D * D; s1 = Wr + (l3 + 2) * D * D; break;
            case 3: s0 = Wl + (l3 + 1) * D * D; break;
            default: s0 = Wr + (l3 + 1) * D * D; break;
        }
        bf16x8 hi, lo;
        #pragma unroll
        for (int e = 0; e < 8; ++e) {
            float v = s0[r * D + c + e];
            if (s1) v += s1[r * D + c + e];
            bf16 hh = (bf16)v;
            hi[e] = hh;
            lo[e] = (bf16)(v - (float)hh);
        }
        bf16* base = wbuf + (size_t)l * 10 * D * D;
        ((bf16x8*)(base + (size_t)(2 * mat) * D * D))[q] = hi;
        ((bf16x8*)(base + (size_t)(2 * mat + 1) * D * D))[q] = lo;
        return;
    }
    b -= 120;
    if (b < 2) {
        int idx = b * 256 + threadIdx.x;
        if (idx >= NLAY * D) return;
        int l = idx >> 7, o = idx & (D - 1);
        bbuf[l * 2 * D + o]     = bl[(size_t)(l * 3 + 0) * D + o] + bl[(size_t)(l * 3 + 2) * D + o];
        bbuf[l * 2 * D + D + o] = bl[(size_t)(l * 3 + 1) * D + o];
        return;
    }
    b -= 2;
    if (b == 0) {
        int t = threadIdx.x;
        if (t <= NB) {
            int lo = 0, hi = nE;
            while (lo < hi) { int mid = (lo + hi) >> 1; if (bEv[mid] < t) lo = mid + 1; else hi = mid; }
            boundsE[t] = lo;
        } else if (t <= 2 * NB + 1) {
            int v = t - NB - 1;
            int lo = 0, hi = nT;
            while (lo < hi) { int mid = (lo + hi) >> 1; if (bTr[mid] < v) lo = mid + 1; else hi = mid; }
            boundsT[v] = lo;
        }
        return;
    }
    b -= 1;
    int idx = b * 256 + threadIdx.x;
    if (idx < 5 * NB * D / 4)
        ((float4*)pooled5)[idx] = make_float4(0.f, 0.f, 0.f, 0.f);
}

// ================= csr_coop: scan p1 -> p23 -> scatter -> build (3 grid syncs) ======
struct CsrArgs {
    const int *sEE, *dEE, *sET, *dET, *sTE, *dTE;
    int nEE, nET, nTE;
    int nbkEE, nblkEE, nbkET, nblkET, nbkTE, nblkTE;
    int cEE, cET, cTE;
    int *cnt_ee, *S_ee, *cnt_et, *S_et, *cnt_te, *S_te;
    int *bsum_ee, *bsum_et, *bsum_te;
    int2 *eb_ee, *eb_et, *eb_te;
    int *off_ee, *adj_ee, *off_et, *adj_et, *off_te, *adj_te;
    int ndEE, ndET, ndTE;
};

__device__ void scan_p1_dev(int b, const CsrArgs& A, int* sh) {
    int nbA = (A.cEE + 1023) >> 10, nbB = (A.cET + 1023) >> 10;
    const int* deg; int* off; int* bsum; int n; int lb;
    if (b < nbA) { deg = A.cnt_ee; off = A.S_ee; bsum = A.bsum_ee; n = A.cEE; lb = b; }
    else if (b < nbA + nbB) { deg = A.cnt_et; off = A.S_et; bsum = A.bsum_et; n = A.cET; lb = b - nbA; }
    else { deg = A.cnt_te; off = A.S_te; bsum = A.bsum_te; n = A.cTE; lb = b - nbA - nbB; }
    int* s = sh;
    int t = threadIdx.x;
    int base = lb * 1024 + t * 4;
    int v[4];
    #pragma unroll
    for (int i = 0; i < 4; ++i) v[i] = (base + i < n) ? deg[base + i] : 0;
    int tot = v[0] + v[1] + v[2] + v[3];
    s[t] = tot;
    __syncthreads();
    for (int st = 1; st < 256; st <<= 1) {
        int x = (t >= st) ? s[t - st] : 0;
        __syncthreads();
        s[t] += x;
        __syncthreads();
    }
    int run = s[t] - tot;
    #pragma unroll
    for (int i = 0; i < 4; ++i) {
        if (base + i < n) off[base + i] = run;
        run += v[i];
    }
    if (t == 255) bsum[lb] = s[255];
    __syncthreads();
}

__device__ void scan_p23_dev(int b, const CsrArgs& A, int* sh) {
    int cbA = (A.cEE + 255) >> 8, cbB = (A.cET + 255) >> 8;
    int* off; const int* bsum; int n; int lb;
    if (b < cbA) { off = A.S_ee; bsum = A.bsum_ee; n = A.cEE; lb = b; }
    else if (b < cbA + cbB) { off = A.S_et; bsum = A.bsum_et; n = A.cET; lb = b - cbA; }
    else { off = A.S_te; bsum = A.bsum_te; n = A.cTE; lb = b - cbA - cbB; }
    int* s = sh;
    int* ex = sh + 256;
    int nb = (n + 1023) >> 10;
    int t = threadIdx.x;
    int v = (t < nb) ? bsum[t] : 0;
    s[t] = v;
    __syncthreads();
    for (int st = 1; st < 256; st <<= 1) {
        int x = (t >= st) ? s[t - st] : 0;
        __syncthreads();
        s[t] += x;
        __syncthreads();
    }
    ex[t] = s[t] - v;
    __syncthreads();
    int i = lb * 256 + t;
    if (i < n) off[i] += ex[i >> 10];
    if (i == 0) off[n] = s[nb - 1];
    __syncthreads();
}

__device__ void scatter_dev(int b, const CsrArgs& A, int* sh) {
    const int* src; const int* dst; const int* S; int2* eb; int E, nbk, nblk, lb;
    if (b < A.nblkEE) { src = A.sEE; dst = A.dEE; S = A.S_ee; eb = A.eb_ee; E = A.nEE; nbk = A.nbkEE; nblk = A.nblkEE; lb = b; }
    else if (b < A.nblkEE + A.nblkET) { src = A.sET; dst = A.dET; S = A.S_et; eb = A.eb_et; E = A.nET; nbk = A.nbkET; nblk = A.nblkET; lb = b - A.nblkEE; }
    else { src = A.sTE; dst = A.dTE; S = A.S_te; eb = A.eb_te; E = A.nTE; nbk = A.nbkTE; nblk = A.nblkTE; lb = b - A.nblkEE - A.nblkET; }
    int* cu = sh;
    for (int k = threadIdx.x; k < nbk; k += 256) cu[k] = S[k * nblk + lb];
    __syncthreads();
    int e0 = lb * EPB, e1 = min(e0 + EPB, E);
    for (int e = e0 + threadIdx.x; e < e1; e += 256) {
        int s = src[e], d = dst[e];
        int p = atomicAdd(&cu[d >> BSH2], 1);
        eb[p] = make_int2(s, d);
    }
    __syncthreads();
}

__device__ void build_dev(int b, const CsrArgs& A, int* sh) {
    const int2* eb; const int* S; int nbk, nblk, ndst, k; int* off; int* adj;
    if (b < A.nbkEE) { eb = A.eb_ee; S = A.S_ee; nbk = A.nbkEE; nblk = A.nblkEE; ndst = A.ndEE; off = A.off_ee; adj = A.adj_ee; k = b; }
    else if (b < A.nbkEE + A.nbkET) { eb = A.eb_et; S = A.S_et; nbk = A.nbkET; nblk = A.nblkET; ndst = A.ndET; off = A.off_et; adj = A.adj_et; k = b - A.nbkEE; }
    else { eb = A.eb_te; S = A.S_te; nbk = A.nbkTE; nblk = A.nblkTE; ndst = A.ndTE; off = A.off_te; adj = A.adj_te; k = b - A.nbkEE - A.nbkET; }
    int* h = sh;          // 512
    int* ps = sh + 512;   // 256
    int* cc = sh + 768;   // 512
    int base = S[k * nblk];
    int end  = (k == nbk - 1) ? S[nbk * nblk] : S[(k + 1) * nblk];
    int d0 = k << BSH2;
    int t = threadIdx.x;
    h[t] = 0; h[t + 256] = 0;
    __syncthreads();
    for (int j = base + t; j < end; j += 256) atomicAdd(&h[eb[j].y - d0], 1);
    __syncthreads();
    int a0 = h[2 * t], a1 = h[2 * t + 1];
    ps[t] = a0 + a1;
    __syncthreads();
    for (int st = 1; st < 256; st <<= 1) {
        int x = (t >= st) ? ps[t - st] : 0;
        __syncthreads();
        ps[t] += x;
        __syncthreads();
    }
    int pe = ps[t] - (a0 + a1);
    int o0 = base + pe, o1 = base + pe + a0;
    cc[2 * t] = o0; cc[2 * t + 1] = o1;
    int nd = min(512, ndst - d0);
    if (2 * t < nd) off[d0 + 2 * t] = o0;
    if (2 * t + 1 < nd) off[d0 + 2 * t + 1] = o1;
    if (t == 0 && k == nbk - 1) off[ndst] = end;
    __syncthreads();
    for (int j = base + t; j < end; j += 256) {
        int2 e = eb[j];
        int p = atomicAdd(&cc[e.y - d0], 1);
        adj[p] = e.x;
    }
    __syncthreads();
}

__global__ void csr_coop(CsrArgs A) {
    __shared__ int sh[1280];
    cg::grid_group grid = cg::this_grid();
    int nb1 = (A.cEE + 1023) >> 10, nb2 = (A.cET + 1023) >> 10, nb3 = (A.cTE + 1023) >> 10;
    int nScan1 = nb1 + nb2 + nb3;
    for (int vb = blockIdx.x; vb < nScan1; vb += gridDim.x) scan_p1_dev(vb, A, sh);
    grid.sync();
    int nScan23 = ((A.cEE + 255) >> 8) + ((A.cET + 255) >> 8) + ((A.cTE + 255) >> 8);
    for (int vb = blockIdx.x; vb < nScan23; vb += gridDim.x) scan_p23_dev(vb, A, sh);
    grid.sync();
    int nScat = A.nblkEE + A.nblkET + A.nblkTE;
    for (int vb = blockIdx.x; vb < nScat; vb += gridDim.x) scatter_dev(vb, A, sh);
    grid.sync();
    int nBld = A.nbkEE + A.nbkET + A.nbkTE;
    for (int vb = blockIdx.x; vb < nBld; vb += gridDim.x) build_dev(vb, A, sh);
}

// ================= merged mean aggregation (3 edge types) + optional root-pool ======
__global__ void agg_all(const bf16* __restrict__ xE, const bf16* __restrict__ xT,
                        const int* __restrict__ offEE, const int* __restrict__ adjEE,
                        const int* __restrict__ offTE, const int* __restrict__ adjTE,
                        const int* __restrict__ offET, const int* __restrict__ adjET,
                        bf16* __restrict__ mEE, bf16* __restrict__ mTE, bf16* __restrict__ mET,
                        int nE, int nT, int aggBlocks,
                        const int* __restrict__ boundsE, const int* __restrict__ boundsT,
                        float* __restrict__ pooled5) {
    __shared__ float red[16][D];
    if ((int)blockIdx.x >= aggBlocks) {
        int idx = (int)blockIdx.x - aggBlocks;          // [0, 2*NB*PSPLIT)
        int j2 = idx / (NB * PSPLIT);                   // 0: xE, 1: xT
        int rem = idx - j2 * NB * PSPLIT;
        int bb = rem / PSPLIT, jj = rem - bb * PSPLIT;
        if (j2 == 0) pool_block_dev(xE, 2, boundsE, bb, jj, pooled5, red);
        else         pool_block_dev(xT, 4, boundsT, bb, jj, pooled5, red);
        return;
    }
    int gw = (blockIdx.x * blockDim.x + threadIdx.x) >> 6;
    int lane = threadIdx.x & 63;
    int qE = (nE + 3) >> 2, qT = (nT + 3) >> 2;
    const bf16* xsrc; const int* off; const int* adj; bf16* out; int ndst;
    if (gw < qE) { xsrc = xE; off = offEE; adj = adjEE; out = mEE; ndst = nE; }
    else if (gw < 2 * qE) { gw -= qE; xsrc = xT; off = offTE; adj = adjTE; out = mTE; ndst = nE; }
    else {
        gw -= 2 * qE;
        if (gw >= qT) return;
        xsrc = xE; off = offET; adj = adjET; out = mET; ndst = nT;
    }
    int sub = lane >> 4;       // 0..3: which dst row
    int sl  = lane & 15;       // 16B chunk within row
    int row = gw * 4 + sub;
    if (row >= ndst) row = ndst - 1;   // duplicate work, identical writes: benign
    int s0 = off[row], s1 = off[row + 1];
    float a[8] = {};
    int j = s0;
    for (; j + 8 <= s1; j += 8) {
        int ii[8];
        #pragma unroll
        for (int u = 0; u < 8; ++u) ii[u] = adj[j + u];
        bf16x8 v[8];
        #pragma unroll
        for (int u = 0; u < 8; ++u) v[u] = ((const bf16x8*)(xsrc + (size_t)ii[u] * D))[sl];
        #pragma unroll
        for (int u = 0; u < 8; ++u)
            #pragma unroll
            for (int e = 0; e < 8; ++e) a[e] += (float)v[u][e];
    }
    for (; j + 4 <= s1; j += 4) {
        int i0 = adj[j], i1 = adj[j + 1], i2 = adj[j + 2], i3 = adj[j + 3];
        bf16x8 v0 = ((const bf16x8*)(xsrc + (size_t)i0 * D))[sl];
        bf16x8 v1 = ((const bf16x8*)(xsrc + (size_t)i1 * D))[sl];
        bf16x8 v2 = ((const bf16x8*)(xsrc + (size_t)i2 * D))[sl];
        bf16x8 v3 = ((const bf16x8*)(xsrc + (size_t)i3 * D))[sl];
        #pragma unroll
        for (int e = 0; e < 8; ++e)
            a[e] += (float)v0[e] + (float)v1[e] + (float)v2[e] + (float)v3[e];
    }
    for (; j < s1; ++j) {
        int i0 = adj[j];
        bf16x8 v0 = ((const bf16x8*)(xsrc + (size_t)i0 * D))[sl];
        #pragma unroll
        for (int e = 0; e < 8; ++e) a[e] += (float)v0[e];
    }
    float inv = 1.0f / fmaxf((float)(s1 - s0), 1.0f);
    bf16x8 o;
    #pragma unroll
    for (int e = 0; e < 8; ++e) o[e] = (bf16)(a[e] * inv);
    ((bf16x8*)(out + (size_t)row * D))[sl] = o;
}

// ================= fused MFMA GEMM: out = bias + sum_s A_s @ W_s^T ==================
__device__ __forceinline__ void gemm_body(const bf16* A0, const bf16* A1, const bf16* A2,
                                          const bf16* Wp, const float* bias, bf16* out,
                                          int M, int nm, int row0, bf16* As) {
    int tid = threadIdx.x;
    int wave = tid >> 6, lane = tid & 63;
    int m = lane & 31, half = lane >> 5;

    f32x16 acc[2];
    #pragma unroll
    for (int rt = 0; rt < 2; ++rt)
        #pragma unroll
        for (int i = 0; i < 16; ++i) acc[rt][i] = 0.f;

    const bf16* Aptr[3] = {A0, A1, A2};
    #pragma unroll
    for (int s = 0; s < 3; ++s) {
        if (s >= nm) break;
        if (s) __syncthreads();
        const bf16* Amat = Aptr[s];
        #pragma unroll
        for (int p = 0; p < 4; ++p) {
            int si = p * 256 + tid;
            int r = si >> 4, u = si & 15;
            int gr = row0 + r; if (gr >= M) gr = M - 1;
            int gc = (u ^ (r & 15)) * 8;
            LOAD16_TO_LDS(Amat + (size_t)gr * D + gc, As + (size_t)(p * 4 + wave) * 512);
        }
        const bf16* wph = Wp + (size_t)(2 * s) * D * D + ((size_t)wave * 512 + lane) * 8;
        const bf16* wpl = wph + D * D;
        bf16x8 bh_c  = *(const bf16x8*)(wph);
        bf16x8 blo_c = *(const bf16x8*)(wpl);
        __syncthreads();

        #pragma unroll 1
        for (int t = 0; t < 8; ++t) {
            bf16x8 bh_n, blo_n;
            if (t < 7) {
                bh_n  = *(const bf16x8*)(wph + (t + 1) * 512);
                blo_n = *(const bf16x8*)(wpl + (t + 1) * 512);
            }
            bf16x8 af[2];
            #pragma unroll
            for (int rt = 0; rt < 2; ++rt) {
                int r = rt * 32 + m;
                int c = t * 2 + half;
                af[rt] = *(const bf16x8*)(As + ((size_t)r * 16 + (c ^ (r & 15))) * 8);
            }
            acc[0] = __builtin_amdgcn_mfma_f32_32x32x16_bf16(af[0], bh_c,  acc[0], 0, 0, 0);
            acc[1] = __builtin_amdgcn_mfma_f32_32x32x16_bf16(af[1], bh_c,  acc[1], 0, 0, 0);
            acc[0] = __builtin_amdgcn_mfma_f32_32x32x16_bf16(af[0], blo_c, acc[0], 0, 0, 0);
            acc[1] = __builtin_amdgcn_mfma_f32_32x32x16_bf16(af[1], blo_c, acc[1], 0, 0, 0);
            bh_c = bh_n; blo_c = blo_n;
        }
    }

    int col = wave * 32 + m;
    float bv = bias[col];
    #pragma unroll
    for (int rt = 0; rt < 2; ++rt) {
        #pragma unroll
        for (int r = 0; r < 16; ++r) {
            int row = row0 + rt * 32 + (r & 3) + 8 * (r >> 2) + 4 * half;
            if (row < M) out[(size_t)row * D + col] = (bf16)(acc[rt][r] + bv);
        }
    }
}

__global__ __launch_bounds__(256) void gemm_all(const bf16* __restrict__ eA0, const bf16* __restrict__ eA1,
                                                const bf16* __restrict__ eA2, const bf16* __restrict__ eW,
                                                const float* __restrict__ eB, bf16* __restrict__ eOut,
                                                int Me, int bE,
                                                const bf16* __restrict__ tA0, const bf16* __restrict__ tA1,
                                                const bf16* __restrict__ tW, const float* __restrict__ tB,
                                                bf16* __restrict__ tOut, int Mt) {
    __shared__ bf16 As[64 * 128];   // 16 KB
    if ((int)blockIdx.x < bE)
        gemm_body(eA0, eA1, eA2, eW, eB, eOut, Me, 3, blockIdx.x * 64, As);
    else
        gemm_body(tA0, tA1, (const bf16*)nullptr, tW, tB, tOut, Mt, 2,
                  ((int)blockIdx.x - bE) * 64, As);
}

// ================= finish_coop: pool 3 m-matrices (slots 0,1,3) + grid sync + tail ==
struct FinArgs {
    const bf16 *m_ee, *m_te, *m_et;
    const int *boundsE, *boundsT;
    float* pooled5;
    const float *Wl, *Wr, *bl, *W1, *b1, *W2, *b2;
    float* out;
};

__global__ void finish_coop(FinArgs A) {
    __shared__ float red[16][D];   // 8 KB; tail aliases part of it
    cg::grid_group grid = cg::this_grid();
    for (int vb = blockIdx.x; vb < 3 * NB * PSPLIT; vb += gridDim.x) {
        int s3 = vb / (NB * PSPLIT);
        int rem = vb - s3 * NB * PSPLIT;
        int b = rem / PSPLIT, j = rem - b * PSPLIT;
        if (s3 == 0)      pool_block_dev(A.m_ee, 0, A.boundsE, b, j, A.pooled5, red);
        else if (s3 == 1) pool_block_dev(A.m_te, 1, A.boundsE, b, j, A.pooled5, red);
        else              pool_block_dev(A.m_et, 3, A.boundsT, b, j, A.pooled5, red);
    }
    grid.sync();
    if ((int)blockIdx.x >= NB) return;
    // ---- tail: layer-3 GEMM on pooled vectors (exact fp32) + MLP head ----
    float* p5 = &red[0][0];        // 5*D floats
    float* hp = p5 + 5 * D;        // D floats
    float* hh = hp + D;            // D floats  (total 7*D = 896 <= 2048 floats)
    int b = blockIdx.x, t = threadIdx.x;   // 256 threads; work on t<128
    if (t < D) {
        #pragma unroll
        for (int s = 0; s < 5; ++s) p5[s * D + t] = A.pooled5[(size_t)(s * NB + b) * D + t];
    }
    __syncthreads();
    const float* Wl = A.Wl; const float* Wr = A.Wr; const float* bl = A.bl;
    if (t < D) {
        float ce = (float)(A.boundsE[b + 1] - A.boundsE[b]);
        float ct = (float)(A.boundsT[b + 1] - A.boundsT[b]);
        float s = ce * (bl[6 * D + t] + bl[8 * D + t]) + ct * bl[7 * D + t];
        const float* w0  = Wl + (size_t)6 * D * D + (size_t)t * D;
        const float* w2  = Wl + (size_t)8 * D * D + (size_t)t * D;
        const float* wr0 = Wr + (size_t)6 * D * D + (size_t)t * D;
        const float* wr2 = Wr + (size_t)8 * D * D + (size_t)t * D;
        const float* w1m = Wl + (size_t)7 * D * D + (size_t)t * D;
        const float* wr1 = Wr + (size_t)7 * D * D + (size_t)t * D;
        #pragma unroll 4
        for (int k = 0; k < D; ++k)
            s += p5[0 * D + k] * w0[k] + p5[1 * D + k] * w2[k] + p5[2 * D + k] * (wr0[k] + wr2[k])
               + p5[3 * D + k] * w1m[k] + p5[4 * D + k] * wr1[k];
        hp[t] = s;
    }
    __syncthreads();
    if (t < D) {
        float s1 = A.b1[t];
        const float* u = A.W1 + (size_t)t * D;
        #pragma unroll 4
        for (int k = 0; k < D; ++k) s1 += hp[k] * u[k];
        hh[t] = fmaxf(s1, 0.f);
    }
    __syncthreads();
    if (t < OUTD) {
        float s2 = A.b2[t];
        const float* v = A.W2 + (size_t)t * D;
        #pragma unroll 4
        for (int k = 0; k < D; ++k) s2 += hh[k] * v[k];
        A.out[b * OUTD + t] = s2;
    }
}

extern "C" void kernel_launch(void* const* d_in, const int* in_sizes, int n_in,
                              void* d_out, int out_size, void* d_ws, size_t ws_size,
                              hipStream_t stream) {
    const int* event_ids   = (const int*)d_in[0];
    const int* trace_ids   = (const int*)d_in[1];
    const int* e2e_src     = (const int*)d_in[2];
    const int* e2e_dst     = (const int*)d_in[3];
    const int* e2t_src     = (const int*)d_in[4];
    const int* e2t_dst     = (const int*)d_in[5];
    const int* t2e_src     = (const int*)d_in[6];
    const int* t2e_dst     = (const int*)d_in[7];
    const int* event_batch = (const int*)d_in[8];
    const int* trace_batch = (const int*)d_in[9];
    const float* emb_event = (const float*)d_in[10];
    const float* emb_trace = (const float*)d_in[11];
    const float* Wl        = (const float*)d_in[12];
    const float* bl        = (const float*)d_in[13];
    const float* Wr        = (const float*)d_in[14];
    const float* W1        = (const float*)d_in[15];
    const float* b1        = (const float*)d_in[16];
    const float* W2        = (const float*)d_in[17];
    const float* b2        = (const float*)d_in[18];

    const int NE = in_sizes[0];
    const int NT = in_sizes[1];
    const int EE = in_sizes[2];
    const int ET = in_sizes[4];
    const int TE = in_sizes[6];

    // bucket geometry
    const int nbkEE = (NE + 511) >> BSH2, nblkEE = (EE + EPB - 1) / EPB;
    const int nbkET = (NT + 511) >> BSH2, nblkET = (ET + EPB - 1) / EPB;
    const int nbkTE = (NE + 511) >> BSH2, nblkTE = (TE + EPB - 1) / EPB;
    const int cEE = nbkEE * nblkEE, cET = nbkET * nblkET, cTE = nbkTE * nblkTE;

    // ---- workspace carve-up ----
    size_t cur = 0;
    auto alloc = [&](size_t bytes) -> void* {
        cur = (cur + 255) & ~(size_t)255;
        void* p = (char*)d_ws + cur;
        cur += bytes;
        return p;
    };
    bf16* x_event   = (bf16*)alloc((size_t)NE * D * 2);
    bf16* x_trace   = (bf16*)alloc((size_t)NT * D * 2);
    bf16* nx_event  = (bf16*)alloc((size_t)NE * D * 2);
    bf16* nx_trace  = (bf16*)alloc((size_t)NT * D * 2);
    bf16* m_ee      = (bf16*)alloc((size_t)NE * D * 2);   // aliased by eb_ee pre-layers
    bf16* m_te      = (bf16*)alloc((size_t)NE * D * 2);   // aliased by eb_et pre-layers
    bf16* m_et      = (bf16*)alloc((size_t)NT * D * 2);   // aliased by eb_te pre-layers
    bf16* wbuf      = (bf16*)alloc((size_t)NLAY * 10 * D * D * 2);
    float* bbuf     = (float*)alloc((size_t)NLAY * 2 * D * 4);
    float* pooled5  = (float*)alloc((size_t)5 * NB * D * 4);
    int* boundsE = (int*)alloc((size_t)(NB + 1) * 4);
    int* boundsT = (int*)alloc((size_t)(NB + 1) * 4);
    int* off_ee = (int*)alloc((size_t)(NE + 1) * 4);
    int* adj_ee = (int*)alloc((size_t)EE * 4);
    int* off_et = (int*)alloc((size_t)(NT + 1) * 4);
    int* adj_et = (int*)alloc((size_t)ET * 4);
    int* off_te = (int*)alloc((size_t)(NE + 1) * 4);
    int* adj_te = (int*)alloc((size_t)TE * 4);
    int* cnt_ee = (int*)alloc((size_t)cEE * 4);
    int* S_ee   = (int*)alloc((size_t)(cEE + 1) * 4);
    int* cnt_et = (int*)alloc((size_t)cET * 4);
    int* S_et   = (int*)alloc((size_t)(cET + 1) * 4);
    int* cnt_te = (int*)alloc((size_t)cTE * 4);
    int* S_te   = (int*)alloc((size_t)(cTE + 1) * 4);
    int* bsum_ee = (int*)alloc(((size_t)(cEE + 1023) / 1024 + 1) * 4);
    int* bsum_et = (int*)alloc(((size_t)(cET + 1023) / 1024 + 1) * 4);
    int* bsum_te = (int*)alloc(((size_t)(cTE + 1023) / 1024 + 1) * 4);
    // edge pair buffers alias m_* (disjoint lifetime: CSR build ends before first agg)
    int2* eb_ee = (int2*)m_ee;   // EE*8 = 8MB  <= NE*D*2 = 25.6MB
    int2* eb_et = (int2*)m_te;   // ET*8 = 4MB  <= 25.6MB
    int2* eb_te = (int2*)m_et;   // TE*8 = 4MB  <= NT*D*2 = 5.1MB
    (void)ws_size; (void)n_in; (void)out_size;

    // ---- front: gather + hist + weight/bias prep + bounds + zero pooled5 (1 launch) -
    const int nGather = ((NE + NT) * 32 + 255) / 256;
    const int nblkH = nblkEE + nblkET + nblkTE;
    front_all<<<nGather + nblkH + 120 + 2 + 1 + 40, 256, 0, stream>>>(
        emb_event, event_ids, x_event, NE, emb_trace, trace_ids, x_trace, NT,
        event_batch, trace_batch, boundsE, boundsT,
        e2e_dst, EE, nbkEE, nblkEE, cnt_ee,
        e2t_dst, ET, nbkET, nblkET, cnt_et,
        t2e_dst, TE, nbkTE, nblkTE, cnt_te,
        Wl, Wr, bl, wbuf, bbuf, pooled5, nGather);

    // ---- CSR build: one cooperative kernel (scan p1 -> p23 -> scatter -> build) ----
    CsrArgs ca;
    ca.sEE = e2e_src; ca.dEE = e2e_dst; ca.sET = e2t_src; ca.dET = e2t_dst;
    ca.sTE = t2e_src; ca.dTE = t2e_dst;
    ca.nEE = EE; ca.nET = ET; ca.nTE = TE;
    ca.nbkEE = nbkEE; ca.nblkEE = nblkEE; ca.nbkET = nbkET; ca.nblkET = nblkET;
    ca.nbkTE = nbkTE; ca.nblkTE = nblkTE;
    ca.cEE = cEE; ca.cET = cET; ca.cTE = cTE;
    ca.cnt_ee = cnt_ee; ca.S_ee = S_ee; ca.cnt_et = cnt_et; ca.S_et = S_et;
    ca.cnt_te = cnt_te; ca.S_te = S_te;
    ca.bsum_ee = bsum_ee; ca.bsum_et = bsum_et; ca.bsum_te = bsum_te;
    ca.eb_ee = eb_ee; ca.eb_et = eb_et; ca.eb_te = eb_te;
    ca.off_ee = off_ee; ca.adj_ee = adj_ee; ca.off_et = off_et; ca.adj_et = adj_et;
    ca.off_te = off_te; ca.adj_te = adj_te;
    ca.ndEE = NE; ca.ndET = NT; ca.ndTE = NE;
    {
        void* kp[] = { &ca };
        hipLaunchCooperativeKernel((void*)csr_coop, dim3(CSRGRID), dim3(256), kp, 0, stream);
    }

    // ---- layers 1..2: agg + MFMA GEMM; layer 3: agg (+root-pool blocks) only ----
    const int qE = (NE + 3) >> 2, qT = (NT + 3) >> 2;
    const int aggBlocks = (2 * qE + qT + 3) / 4;
    const int bE = (NE + 63) / 64, bT = (NT + 63) / 64;
    for (int l = 0; l < NLAY; ++l) {
        int extra = (l == NLAY - 1) ? 2 * NB * PSPLIT : 0;
        agg_all<<<aggBlocks + extra, 256, 0, stream>>>(x_event, x_trace,
                                                       off_ee, adj_ee, off_te, adj_te, off_et, adj_et,
                                                       m_ee, m_te, m_et, NE, NT, aggBlocks,
                                                       boundsE, boundsT, pooled5);
        if (l < NLAY - 1) {
            const bf16* wl_ev = wbuf + (size_t)l * 10 * D * D;
            const bf16* wl_tr = wl_ev + (size_t)6 * D * D;
            const float* be = bbuf + (size_t)l * 2 * D;
            const float* bt = be + D;
            gemm_all<<<bE + bT, 256, 0, stream>>>(m_ee, m_te, x_event, wl_ev, be, nx_event, NE, bE,
                                                  m_et, x_trace, wl_tr, bt, nx_trace, NT);
            bf16* t;
            t = x_event; x_event = nx_event; nx_event = t;
            t = x_trace; x_trace = nx_trace; nx_trace = t;
        }
    }

    // ---- finish: pool 3 m-matrices + tail GEMM/head in one cooperative kernel ----
    FinArgs fa;
    fa.m_ee = m_ee; fa.m_te = m_te; fa.m_et = m_et;
    fa.boundsE = boundsE; fa.boundsT = boundsT;
    fa.pooled5 = pooled5;
    fa.Wl = Wl; fa.Wr = Wr; fa.bl = bl;
    fa.W1 = W1; fa.b1 = b1; fa.W2 = W2; fa.b2 = b2;
    fa.out = (float*)d_out;
    {
        void* kp[] = { &fa };
        hipLaunchCooperativeKernel((void*)finish_coop, dim3(FINGRID), dim3(256), kp, 0, stream);
    }
}

// Round 15
// 558.969 us; speedup vs baseline: 1.4981x; 1.4981x over previous
//
#include <hip/hip_runtime.h>
#include <hip/hip_bf16.h>

// HeteroGraphEncoder: 3-layer hetero GraphSAGE + pool + MLP head.
// bf16 activations/weights (hi/lo compensated), fp32 accumulation.
// CSR build via LDS-privatized two-level counting sort (no global atomics).
// Layer 3 uses pool-before-GEMM (linearity); pooling via precomputed batch bounds.
// Launch-count minimized: front_all fuses gather+bounds+prep+hist+zero (12 nodes).
// r14 lesson: cooperative-kernel consolidation regresses (grid.sync + occupancy cap);
// this is the r13 champion structure.
// NE=1e5, NT=2e4, E=2e6, D=128, B=64, L=3.

#define D 128
#define NB 64
#define OUTD 64
#define NLAY 3
#define EPB 4096    // edges per block in bucket build
#define BSH2 9      // 512 dsts per bucket
#define PSPLIT 4    // sub-blocks per (source,batch) in pooling

typedef __bf16 bf16;
typedef __bf16 bf16x4 __attribute__((ext_vector_type(4)));
typedef __bf16 bf16x8 __attribute__((ext_vector_type(8)));
typedef float  f32x16 __attribute__((ext_vector_type(16)));

#define LOAD16_TO_LDS(gp, lp) \
    __builtin_amdgcn_global_load_lds((const __attribute__((address_space(1))) void*)(gp), \
                                     (__attribute__((address_space(3))) void*)(lp), 16, 0, 0)

// ---------------- pool helper: stream contiguous rows of one source ----------------
__device__ __forceinline__ void pool_block_dev(const bf16* __restrict__ x, int s,
                                               const int* __restrict__ bounds, int b, int j,
                                               float* __restrict__ pooled5, float red[16][D]) {
    int start = bounds[b], end = bounds[b + 1];
    int len = end - start;
    if (len <= 0) return;
    int r0 = start + (int)(((long long)len * j) / PSPLIT);
    int r1 = start + (int)(((long long)len * (j + 1)) / PSPLIT);
    if (r0 >= r1) return;
    int slot = threadIdx.x >> 4;   // 0..15: row slot
    int ch   = threadIdx.x & 15;   // 16B col chunk
    float a[8] = {};
    for (int r = r0 + slot; r < r1; r += 16) {
        bf16x8 v = ((const bf16x8*)(x + (size_t)r * D))[ch];
        #pragma unroll
        for (int e = 0; e < 8; ++e) a[e] += (float)v[e];
    }
    #pragma unroll
    for (int e = 0; e < 8; ++e) red[slot][ch * 8 + e] = a[e];
    __syncthreads();
    int c = threadIdx.x;
    if (c < D) {
        float ssum = 0.f;
        #pragma unroll
        for (int k = 0; k < 16; ++k) ssum += red[k][c];
        atomicAdd(&pooled5[(size_t)s * NB * D + b * D + c], ssum);
    }
}

// ================= front_all: gather + bounds + weight prep + bucket hist + zero ====
// All parts independent; streaming or LDS-local atomics only (no global atomics).
__global__ void front_all(const float* __restrict__ embE, const int* __restrict__ idsE,
                          bf16* __restrict__ xE, int nE,
                          const float* __restrict__ embT, const int* __restrict__ idsT,
                          bf16* __restrict__ xT, int nT,
                          const int* __restrict__ bEv, const int* __restrict__ bTr,
                          int* __restrict__ boundsE, int* __restrict__ boundsT,
                          const int* __restrict__ dEE, int nEE, int nbkEE, int nblkEE,
                          int* __restrict__ cntEE,
                          const int* __restrict__ dET, int nET, int nbkET, int nblkET,
                          int* __restrict__ cntET,
                          const int* __restrict__ dTE, int nTE, int nbkTE, int nblkTE,
                          int* __restrict__ cntTE,
                          const float* __restrict__ Wl, const float* __restrict__ Wr,
                          const float* __restrict__ bl,
                          bf16* __restrict__ wbuf, float* __restrict__ bbuf,
                          float* __restrict__ pooled5, int nGather) {
    __shared__ int h[256];
    int b = blockIdx.x;
    if (b < nGather) {
        // ---- embedding gather fp32 -> bf16 (vectorized) ----
        int idx = b * 256 + threadIdx.x;
        const float* emb; const int* ids; bf16* x;
        int tE = nE * 32;
        if (idx < tE) { emb = embE; ids = idsE; x = xE; }
        else {
            idx -= tE;
            if (idx >= nT * 32) return;
            emb = embT; ids = idsT; x = xT;
        }
        int r = idx >> 5, v = idx & 31;
        float4 f = ((const float4*)(emb + (size_t)ids[r] * D))[v];
        bf16x4 o;
        o[0] = (bf16)f.x; o[1] = (bf16)f.y; o[2] = (bf16)f.z; o[3] = (bf16)f.w;
        ((bf16x4*)(x + (size_t)r * D))[v] = o;
        return;
    }
    b -= nGather;
    int nblkH = nblkEE + nblkET + nblkTE;
    if (b < nblkH) {
        // ---- per-block LDS bucket histogram (bucket = dst>>9), bucket-major cnt ----
        const int* dst; int E, nbk, nblk, lb; int* cnt;
        if (b < nblkEE) { dst = dEE; E = nEE; nbk = nbkEE; nblk = nblkEE; cnt = cntEE; lb = b; }
        else if (b < nblkEE + nblkET) { dst = dET; E = nET; nbk = nbkET; nblk = nblkET; cnt = cntET; lb = b - nblkEE; }
        else { dst = dTE; E = nTE; nbk = nbkTE; nblk = nblkTE; cnt = cntTE; lb = b - nblkEE - nblkET; }
        h[threadIdx.x] = 0;
        __syncthreads();
        int e0 = lb * EPB, e1 = min(e0 + EPB, E);
        for (int e = e0 + threadIdx.x; e < e1; e += 256) atomicAdd(&h[dst[e] >> BSH2], 1);
        __syncthreads();
        for (int k = threadIdx.x; k < nbk; k += 256) cnt[k * nblk + lb] = h[k];
        return;
    }
    b -= nblkH;
    if (b < 120) {
        // ---- weight prep: hi/lo split, packed in MFMA fragment order ----
        // mat 0: Wl0  mat 1: Wl2  mat 2: Wr0+Wr2  mat 3: Wl1  mat 4: Wr1
        int idx = b * 256 + threadIdx.x;  // NLAY*5*2048 = 30720
        if (idx >= NLAY * 5 * 2048) return;
        int l = idx / (5 * 2048);
        int rem = idx - l * 5 * 2048;
        int mat = rem >> 11;
        int q = rem & 2047;
        int lane = q & 63, t = (q >> 6) & 7, w = q >> 9;
        int r = w * 32 + (lane & 31);
        int c = t * 16 + (lane >> 5) * 8;
        size_t l3 = (size_t)l * 3;
        const float* s0;
        const float* s1 = nullptr;
        switch (mat) {
            case 0: s0 = Wl + (l3 + 0) * D * D; break;
            case 1: s0 = Wl + (l3 + 2) * D * D; break;
            case 2: s0 = Wr + (l3 + 0) * D * D; s1 = Wr + (l3 + 2) * D * D; break;
            case 3: s0 = Wl + (l3 + 1) * D * D; break;
            default: s0 = Wr + (l3 + 1) * D * D; break;
        }
        bf16x8 hi, lo;
        #pragma unroll
        for (int e = 0; e < 8; ++e) {
            float v = s0[r * D + c + e];
            if (s1) v += s1[r * D + c + e];
            bf16 hh = (bf16)v;
            hi[e] = hh;
            lo[e] = (bf16)(v - (float)hh);
        }
        bf16* base = wbuf + (size_t)l * 10 * D * D;
        ((bf16x8*)(base + (size_t)(2 * mat) * D * D))[q] = hi;
        ((bf16x8*)(base + (size_t)(2 * mat + 1) * D * D))[q] = lo;
        return;
    }
    b -= 120;
    if (b < 2) {
        // ---- bias prep ----
        int idx = b * 256 + threadIdx.x;  // NLAY*D = 384
        if (idx >= NLAY * D) return;
        int l = idx >> 7, o = idx & (D - 1);
        bbuf[l * 2 * D + o]     = bl[(size_t)(l * 3 + 0) * D + o] + bl[(size_t)(l * 3 + 2) * D + o];
        bbuf[l * 2 * D + D + o] = bl[(size_t)(l * 3 + 1) * D + o];
        return;
    }
    b -= 2;
    if (b == 0) {
        // ---- batch bounds (131 binary searches) ----
        int t = threadIdx.x;
        if (t <= NB) {
            int lo = 0, hi = nE;
            while (lo < hi) { int mid = (lo + hi) >> 1; if (bEv[mid] < t) lo = mid + 1; else hi = mid; }
            boundsE[t] = lo;
        } else if (t <= 2 * NB + 1) {
            int v = t - NB - 1;
            int lo = 0, hi = nT;
            while (lo < hi) { int mid = (lo + hi) >> 1; if (bTr[mid] < v) lo = mid + 1; else hi = mid; }
            boundsT[v] = lo;
        }
        return;
    }
    b -= 1;
    // ---- zero pooled5: 40 blocks x 256 threads x float4 = 40960 floats ----
    int idx = b * 256 + threadIdx.x;
    if (idx < 5 * NB * D / 4)
        ((float4*)pooled5)[idx] = make_float4(0.f, 0.f, 0.f, 0.f);
}

// ---------------- scan phase 1 (per-1024-chunk) over the 3 count arrays -------------
__global__ void scan_p1_all(const int* __restrict__ dA, int* __restrict__ oA, int* __restrict__ sA, int nA,
                            const int* __restrict__ dB, int* __restrict__ oB, int* __restrict__ sB, int nB,
                            const int* __restrict__ dC, int* __restrict__ oC, int* __restrict__ sC, int nC) {
    int nbA = (nA + 1023) >> 10, nbB = (nB + 1023) >> 10;
    int b = blockIdx.x;
    const int* deg; int* off; int* bsum; int n; int lb;
    if (b < nbA) { deg = dA; off = oA; bsum = sA; n = nA; lb = b; }
    else if (b < nbA + nbB) { deg = dB; off = oB; bsum = sB; n = nB; lb = b - nbA; }
    else { deg = dC; off = oC; bsum = sC; n = nC; lb = b - nbA - nbB; }
    __shared__ int s[256];
    int t = threadIdx.x;
    int base = lb * 1024 + t * 4;
    int v[4];
    #pragma unroll
    for (int i = 0; i < 4; ++i) v[i] = (base + i < n) ? deg[base + i] : 0;
    int tot = v[0] + v[1] + v[2] + v[3];
    s[t] = tot;
    __syncthreads();
    for (int st = 1; st < 256; st <<= 1) {
        int x = (t >= st) ? s[t - st] : 0;
        __syncthreads();
        s[t] += x;
        __syncthreads();
    }
    int run = s[t] - tot;
    #pragma unroll
    for (int i = 0; i < 4; ++i) {
        if (base + i < n) off[base + i] = run;
        run += v[i];
    }
    if (t == 255) bsum[lb] = s[255];
}

// ---------------- scan phases 2+3 fused: each block re-scans bsum locally -----------
__global__ void scan_p23_all(int* __restrict__ oA, const int* __restrict__ sA, int nA,
                             int* __restrict__ oB, const int* __restrict__ sB, int nB,
                             int* __restrict__ oC, const int* __restrict__ sC, int nC) {
    int cbA = (nA + 255) >> 8, cbB = (nB + 255) >> 8;
    int b = blockIdx.x;
    int* off; const int* bsum; int n; int lb;
    if (b < cbA) { off = oA; bsum = sA; n = nA; lb = b; }
    else if (b < cbA + cbB) { off = oB; bsum = sB; n = nB; lb = b - cbA; }
    else { off = oC; bsum = sC; n = nC; lb = b - cbA - cbB; }
    __shared__ int s[256];
    __shared__ int ex[256];
    int nb = (n + 1023) >> 10;   // <= 256 for all our arrays
    int t = threadIdx.x;
    int v = (t < nb) ? bsum[t] : 0;
    s[t] = v;
    __syncthreads();
    for (int st = 1; st < 256; st <<= 1) {
        int x = (t >= st) ? s[t - st] : 0;
        __syncthreads();
        s[t] += x;
        __syncthreads();
    }
    ex[t] = s[t] - v;   // exclusive
    __syncthreads();
    int i = lb * 256 + t;
    if (i < n) off[i] += ex[i >> 10];
    if (i == 0) off[n] = s[nb - 1];
}

// ---------------- P2: scatter (src,dst) into bucket-ordered ebuf, LDS cursors -------
__global__ void bkt_scatter_all(const int* __restrict__ sEE, const int* __restrict__ dEE,
                                int nEE, int nbkEE, int nblkEE, const int* __restrict__ SEE,
                                int2* __restrict__ ebEE,
                                const int* __restrict__ sET, const int* __restrict__ dET,
                                int nET, int nbkET, int nblkET, const int* __restrict__ SET,
                                int2* __restrict__ ebET,
                                const int* __restrict__ sTE, const int* __restrict__ dTE,
                                int nTE, int nbkTE, int nblkTE, const int* __restrict__ STE,
                                int2* __restrict__ ebTE) {
    __shared__ int cu[256];
    int b = blockIdx.x;
    const int* src; const int* dst; const int* S; int2* eb; int E, nbk, nblk, lb;
    if (b < nblkEE) { src = sEE; dst = dEE; S = SEE; eb = ebEE; E = nEE; nbk = nbkEE; nblk = nblkEE; lb = b; }
    else if (b < nblkEE + nblkET) { src = sET; dst = dET; S = SET; eb = ebET; E = nET; nbk = nbkET; nblk = nblkET; lb = b - nblkEE; }
    else { src = sTE; dst = dTE; S = STE; eb = ebTE; E = nTE; nbk = nbkTE; nblk = nblkTE; lb = b - nblkEE - nblkET; }
    for (int k = threadIdx.x; k < nbk; k += 256) cu[k] = S[k * nblk + lb];
    __syncthreads();
    int e0 = lb * EPB, e1 = min(e0 + EPB, E);
    for (int e = e0 + threadIdx.x; e < e1; e += 256) {
        int s = src[e], d = dst[e];
        int p = atomicAdd(&cu[d >> BSH2], 1);
        eb[p] = make_int2(s, d);
    }
}

// ---------------- P3: per-bucket CSR finalize: LDS hist+scan -> off, adj ------------
__global__ void csr_build_all(const int2* __restrict__ ebEE, const int* __restrict__ SEE,
                              int nbkEE, int nblkEE, int ndEE,
                              int* __restrict__ offEE, int* __restrict__ adjEE,
                              const int2* __restrict__ ebET, const int* __restrict__ SET,
                              int nbkET, int nblkET, int ndET,
                              int* __restrict__ offET, int* __restrict__ adjET,
                              const int2* __restrict__ ebTE, const int* __restrict__ STE,
                              int nbkTE, int nblkTE, int ndTE,
                              int* __restrict__ offTE, int* __restrict__ adjTE) {
    __shared__ int h[512];
    __shared__ int ps[256];
    __shared__ int cc[512];
    int b = blockIdx.x;
    const int2* eb; const int* S; int nbk, nblk, ndst, k; int* off; int* adj;
    if (b < nbkEE) { eb = ebEE; S = SEE; nbk = nbkEE; nblk = nblkEE; ndst = ndEE; off = offEE; adj = adjEE; k = b; }
    else if (b < nbkEE + nbkET) { eb = ebET; S = SET; nbk = nbkET; nblk = nblkET; ndst = ndET; off = offET; adj = adjET; k = b - nbkEE; }
    else { eb = ebTE; S = STE; nbk = nbkTE; nblk = nblkTE; ndst = ndTE; off = offTE; adj = adjTE; k = b - nbkEE - nbkET; }
    int base = S[k * nblk];
    int end  = (k == nbk - 1) ? S[nbk * nblk] : S[(k + 1) * nblk];
    int d0 = k << BSH2;
    int t = threadIdx.x;
    h[t] = 0; h[t + 256] = 0;
    __syncthreads();
    for (int j = base + t; j < end; j += 256) atomicAdd(&h[eb[j].y - d0], 1);
    __syncthreads();
    int a0 = h[2 * t], a1 = h[2 * t + 1];
    ps[t] = a0 + a1;
    __syncthreads();
    for (int st = 1; st < 256; st <<= 1) {
        int x = (t >= st) ? ps[t - st] : 0;
        __syncthreads();
        ps[t] += x;
        __syncthreads();
    }
    int pe = ps[t] - (a0 + a1);           // exclusive pair prefix
    int o0 = base + pe, o1 = base + pe + a0;
    cc[2 * t] = o0; cc[2 * t + 1] = o1;
    int nd = min(512, ndst - d0);
    if (2 * t < nd) off[d0 + 2 * t] = o0;
    if (2 * t + 1 < nd) off[d0 + 2 * t + 1] = o1;
    if (t == 0 && k == nbk - 1) off[ndst] = end;
    __syncthreads();
    for (int j = base + t; j < end; j += 256) {
        int2 e = eb[j];
        int p = atomicAdd(&cc[e.y - d0], 1);
        adj[p] = e.x;
    }
}

// ---------------- merged mean aggregation (3 edge types) + optional root-pool -------
// Layer 3 appends 2*NB*PSPLIT blocks pooling the root tables (xE->slot2, xT->slot4).
__global__ void agg_all(const bf16* __restrict__ xE, const bf16* __restrict__ xT,
                        const int* __restrict__ offEE, const int* __restrict__ adjEE,
                        const int* __restrict__ offTE, const int* __restrict__ adjTE,
                        const int* __restrict__ offET, const int* __restrict__ adjET,
                        bf16* __restrict__ mEE, bf16* __restrict__ mTE, bf16* __restrict__ mET,
                        int nE, int nT, int aggBlocks,
                        const int* __restrict__ boundsE, const int* __restrict__ boundsT,
                        float* __restrict__ pooled5) {
    __shared__ float red[16][D];
    if ((int)blockIdx.x >= aggBlocks) {
        int idx = (int)blockIdx.x - aggBlocks;          // [0, 2*NB*PSPLIT)
        int j2 = idx / (NB * PSPLIT);                   // 0: xE, 1: xT
        int rem = idx - j2 * NB * PSPLIT;
        int bb = rem / PSPLIT, jj = rem - bb * PSPLIT;
        if (j2 == 0) pool_block_dev(xE, 2, boundsE, bb, jj, pooled5, red);
        else         pool_block_dev(xT, 4, boundsT, bb, jj, pooled5, red);
        return;
    }
    int gw = (blockIdx.x * blockDim.x + threadIdx.x) >> 6;
    int lane = threadIdx.x & 63;
    int qE = (nE + 3) >> 2, qT = (nT + 3) >> 2;
    const bf16* xsrc; const int* off; const int* adj; bf16* out; int ndst;
    if (gw < qE) { xsrc = xE; off = offEE; adj = adjEE; out = mEE; ndst = nE; }
    else if (gw < 2 * qE) { gw -= qE; xsrc = xT; off = offTE; adj = adjTE; out = mTE; ndst = nE; }
    else {
        gw -= 2 * qE;
        if (gw >= qT) return;
        xsrc = xE; off = offET; adj = adjET; out = mET; ndst = nT;
    }
    int sub = lane >> 4;       // 0..3: which dst row
    int sl  = lane & 15;       // 16B chunk within row
    int row = gw * 4 + sub;
    if (row >= ndst) row = ndst - 1;   // duplicate work, identical writes: benign
    int s0 = off[row], s1 = off[row + 1];
    float a[8] = {};
    int j = s0;
    for (; j + 8 <= s1; j += 8) {
        int ii[8];
        #pragma unroll
        for (int u = 0; u < 8; ++u) ii[u] = adj[j + u];
        bf16x8 v[8];
        #pragma unroll
        for (int u = 0; u < 8; ++u) v[u] = ((const bf16x8*)(xsrc + (size_t)ii[u] * D))[sl];
        #pragma unroll
        for (int u = 0; u < 8; ++u)
            #pragma unroll
            for (int e = 0; e < 8; ++e) a[e] += (float)v[u][e];
    }
    for (; j + 4 <= s1; j += 4) {
        int i0 = adj[j], i1 = adj[j + 1], i2 = adj[j + 2], i3 = adj[j + 3];
        bf16x8 v0 = ((const bf16x8*)(xsrc + (size_t)i0 * D))[sl];
        bf16x8 v1 = ((const bf16x8*)(xsrc + (size_t)i1 * D))[sl];
        bf16x8 v2 = ((const bf16x8*)(xsrc + (size_t)i2 * D))[sl];
        bf16x8 v3 = ((const bf16x8*)(xsrc + (size_t)i3 * D))[sl];
        #pragma unroll
        for (int e = 0; e < 8; ++e)
            a[e] += (float)v0[e] + (float)v1[e] + (float)v2[e] + (float)v3[e];
    }
    for (; j < s1; ++j) {
        int i0 = adj[j];
        bf16x8 v0 = ((const bf16x8*)(xsrc + (size_t)i0 * D))[sl];
        #pragma unroll
        for (int e = 0; e < 8; ++e) a[e] += (float)v0[e];
    }
    float inv = 1.0f / fmaxf((float)(s1 - s0), 1.0f);
    bf16x8 o;
    #pragma unroll
    for (int e = 0; e < 8; ++e) o[e] = (bf16)(a[e] * inv);
    ((bf16x8*)(out + (size_t)row * D))[sl] = o;
}

// ---------------- fused MFMA GEMM body: out = bias + sum_s A_s @ W_s^T --------------
// 256 threads = 4 waves; tile 64x128 (16 KB LDS); JIT double-buffered B fragments.
__device__ __forceinline__ void gemm_body(const bf16* A0, const bf16* A1, const bf16* A2,
                                          const bf16* Wp, const float* bias, bf16* out,
                                          int M, int nm, int row0, bf16* As) {
    int tid = threadIdx.x;
    int wave = tid >> 6, lane = tid & 63;
    int m = lane & 31, half = lane >> 5;

    f32x16 acc[2];
    #pragma unroll
    for (int rt = 0; rt < 2; ++rt)
        #pragma unroll
        for (int i = 0; i < 16; ++i) acc[rt][i] = 0.f;

    const bf16* Aptr[3] = {A0, A1, A2};
    #pragma unroll
    for (int s = 0; s < 3; ++s) {
        if (s >= nm) break;
        if (s) __syncthreads();
        const bf16* Amat = Aptr[s];
        #pragma unroll
        for (int p = 0; p < 4; ++p) {
            int si = p * 256 + tid;
            int r = si >> 4, u = si & 15;
            int gr = row0 + r; if (gr >= M) gr = M - 1;
            int gc = (u ^ (r & 15)) * 8;
            LOAD16_TO_LDS(Amat + (size_t)gr * D + gc, As + (size_t)(p * 4 + wave) * 512);
        }
        const bf16* wph = Wp + (size_t)(2 * s) * D * D + ((size_t)wave * 512 + lane) * 8;
        const bf16* wpl = wph + D * D;
        bf16x8 bh_c  = *(const bf16x8*)(wph);
        bf16x8 blo_c = *(const bf16x8*)(wpl);
        __syncthreads();

        #pragma unroll 1
        for (int t = 0; t < 8; ++t) {
            bf16x8 bh_n, blo_n;
            if (t < 7) {
                bh_n  = *(const bf16x8*)(wph + (t + 1) * 512);
                blo_n = *(const bf16x8*)(wpl + (t + 1) * 512);
            }
            bf16x8 af[2];
            #pragma unroll
            for (int rt = 0; rt < 2; ++rt) {
                int r = rt * 32 + m;
                int c = t * 2 + half;
                af[rt] = *(const bf16x8*)(As + ((size_t)r * 16 + (c ^ (r & 15))) * 8);
            }
            acc[0] = __builtin_amdgcn_mfma_f32_32x32x16_bf16(af[0], bh_c,  acc[0], 0, 0, 0);
            acc[1] = __builtin_amdgcn_mfma_f32_32x32x16_bf16(af[1], bh_c,  acc[1], 0, 0, 0);
            acc[0] = __builtin_amdgcn_mfma_f32_32x32x16_bf16(af[0], blo_c, acc[0], 0, 0, 0);
            acc[1] = __builtin_amdgcn_mfma_f32_32x32x16_bf16(af[1], blo_c, acc[1], 0, 0, 0);
            bh_c = bh_n; blo_c = blo_n;
        }
    }

    int col = wave * 32 + m;
    float bv = bias[col];
    #pragma unroll
    for (int rt = 0; rt < 2; ++rt) {
        #pragma unroll
        for (int r = 0; r < 16; ++r) {
            int row = row0 + rt * 32 + (r & 3) + 8 * (r >> 2) + 4 * half;
            if (row < M) out[(size_t)row * D + col] = (bf16)(acc[rt][r] + bv);
        }
    }
}

__global__ __launch_bounds__(256) void gemm_all(const bf16* __restrict__ eA0, const bf16* __restrict__ eA1,
                                                const bf16* __restrict__ eA2, const bf16* __restrict__ eW,
                                                const float* __restrict__ eB, bf16* __restrict__ eOut,
                                                int Me, int bE,
                                                const bf16* __restrict__ tA0, const bf16* __restrict__ tA1,
                                                const bf16* __restrict__ tW, const float* __restrict__ tB,
                                                bf16* __restrict__ tOut, int Mt) {
    __shared__ bf16 As[64 * 128];   // 16 KB
    if ((int)blockIdx.x < bE)
        gemm_body(eA0, eA1, eA2, eW, eB, eOut, Me, 3, blockIdx.x * 64, As);
    else
        gemm_body(tA0, tA1, (const bf16*)nullptr, tW, tB, tOut, Mt, 2,
                  ((int)blockIdx.x - bE) * 64, As);
}

// ---------------- pooling of the 3 m-matrices (slots 0,1,3) -------------------------
__global__ void pool_m_all(const bf16* __restrict__ m_ee, const bf16* __restrict__ m_te,
                           const bf16* __restrict__ m_et,
                           const int* __restrict__ boundsE, const int* __restrict__ boundsT,
                           float* __restrict__ pooled5) {
    __shared__ float red[16][D];
    int blk = blockIdx.x;
    int s3 = blk / (NB * PSPLIT);                  // 0,1,2
    int rem = blk - s3 * NB * PSPLIT;
    int b = rem / PSPLIT, j = rem - b * PSPLIT;
    if (s3 == 0)      pool_block_dev(m_ee, 0, boundsE, b, j, pooled5, red);
    else if (s3 == 1) pool_block_dev(m_te, 1, boundsE, b, j, pooled5, red);
    else              pool_block_dev(m_et, 3, boundsT, b, j, pooled5, red);
}

// ---------------- tail: layer-3 GEMM on pooled vectors (exact fp32) + MLP head ------
__global__ void tail_kernel(const float* __restrict__ pooled5,
                            const int* __restrict__ boundsE, const int* __restrict__ boundsT,
                            const float* __restrict__ Wl, const float* __restrict__ Wr,
                            const float* __restrict__ bl,
                            const float* __restrict__ W1, const float* __restrict__ b1,
                            const float* __restrict__ W2, const float* __restrict__ b2,
                            float* __restrict__ out) {
    __shared__ float p5[5][D];
    __shared__ float hp[D];
    __shared__ float hh[D];
    int b = blockIdx.x, t = threadIdx.x;  // 128 threads
    #pragma unroll
    for (int s = 0; s < 5; ++s) p5[s][t] = pooled5[(size_t)(s * NB + b) * D + t];
    __syncthreads();
    float ce = (float)(boundsE[b + 1] - boundsE[b]);
    float ct = (float)(boundsT[b + 1] - boundsT[b]);
    float s = ce * (bl[6 * D + t] + bl[8 * D + t]) + ct * bl[7 * D + t];
    const float* w0  = Wl + (size_t)6 * D * D + (size_t)t * D;
    const float* w2  = Wl + (size_t)8 * D * D + (size_t)t * D;
    const float* wr0 = Wr + (size_t)6 * D * D + (size_t)t * D;
    const float* wr2 = Wr + (size_t)8 * D * D + (size_t)t * D;
    const float* w1m = Wl + (size_t)7 * D * D + (size_t)t * D;
    const float* wr1 = Wr + (size_t)7 * D * D + (size_t)t * D;
    #pragma unroll 4
    for (int k = 0; k < D; ++k)
        s += p5[0][k] * w0[k] + p5[1][k] * w2[k] + p5[2][k] * (wr0[k] + wr2[k])
           + p5[3][k] * w1m[k] + p5[4][k] * wr1[k];
    hp[t] = s;
    __syncthreads();
    float s1 = b1[t];
    const float* u = W1 + (size_t)t * D;
    #pragma unroll 4
    for (int k = 0; k < D; ++k) s1 += hp[k] * u[k];
    hh[t] = fmaxf(s1, 0.f);
    __syncthreads();
    if (t < OUTD) {
        float s2 = b2[t];
        const float* v = W2 + (size_t)t * D;
        #pragma unroll 4
        for (int k = 0; k < D; ++k) s2 += hh[k] * v[k];
        out[b * OUTD + t] = s2;
    }
}

extern "C" void kernel_launch(void* const* d_in, const int* in_sizes, int n_in,
                              void* d_out, int out_size, void* d_ws, size_t ws_size,
                              hipStream_t stream) {
    const int* event_ids   = (const int*)d_in[0];
    const int* trace_ids   = (const int*)d_in[1];
    const int* e2e_src     = (const int*)d_in[2];
    const int* e2e_dst     = (const int*)d_in[3];
    const int* e2t_src     = (const int*)d_in[4];
    const int* e2t_dst     = (const int*)d_in[5];
    const int* t2e_src     = (const int*)d_in[6];
    const int* t2e_dst     = (const int*)d_in[7];
    const int* event_batch = (const int*)d_in[8];
    const int* trace_batch = (const int*)d_in[9];
    const float* emb_event = (const float*)d_in[10];
    const float* emb_trace = (const float*)d_in[11];
    const float* Wl        = (const float*)d_in[12];
    const float* bl        = (const float*)d_in[13];
    const float* Wr        = (const float*)d_in[14];
    const float* W1        = (const float*)d_in[15];
    const float* b1        = (const float*)d_in[16];
    const float* W2        = (const float*)d_in[17];
    const float* b2        = (const float*)d_in[18];

    const int NE = in_sizes[0];
    const int NT = in_sizes[1];
    const int EE = in_sizes[2];
    const int ET = in_sizes[4];
    const int TE = in_sizes[6];

    // bucket geometry
    const int nbkEE = (NE + 511) >> BSH2, nblkEE = (EE + EPB - 1) / EPB;
    const int nbkET = (NT + 511) >> BSH2, nblkET = (ET + EPB - 1) / EPB;
    const int nbkTE = (NE + 511) >> BSH2, nblkTE = (TE + EPB - 1) / EPB;
    const int cEE = nbkEE * nblkEE, cET = nbkET * nblkET, cTE = nbkTE * nblkTE;

    // ---- workspace carve-up ----
    size_t cur = 0;
    auto alloc = [&](size_t bytes) -> void* {
        cur = (cur + 255) & ~(size_t)255;
        void* p = (char*)d_ws + cur;
        cur += bytes;
        return p;
    };
    bf16* x_event   = (bf16*)alloc((size_t)NE * D * 2);
    bf16* x_trace   = (bf16*)alloc((size_t)NT * D * 2);
    bf16* nx_event  = (bf16*)alloc((size_t)NE * D * 2);
    bf16* nx_trace  = (bf16*)alloc((size_t)NT * D * 2);
    bf16* m_ee      = (bf16*)alloc((size_t)NE * D * 2);   // aliased by eb_ee pre-layers
    bf16* m_te      = (bf16*)alloc((size_t)NE * D * 2);   // aliased by eb_et pre-layers
    bf16* m_et      = (bf16*)alloc((size_t)NT * D * 2);   // aliased by eb_te pre-layers
    bf16* wbuf      = (bf16*)alloc((size_t)NLAY * 10 * D * D * 2);
    float* bbuf     = (float*)alloc((size_t)NLAY * 2 * D * 4);
    float* pooled5  = (float*)alloc((size_t)5 * NB * D * 4);
    int* boundsE = (int*)alloc((size_t)(NB + 1) * 4);
    int* boundsT = (int*)alloc((size_t)(NB + 1) * 4);
    int* off_ee = (int*)alloc((size_t)(NE + 1) * 4);
    int* adj_ee = (int*)alloc((size_t)EE * 4);
    int* off_et = (int*)alloc((size_t)(NT + 1) * 4);
    int* adj_et = (int*)alloc((size_t)ET * 4);
    int* off_te = (int*)alloc((size_t)(NE + 1) * 4);
    int* adj_te = (int*)alloc((size_t)TE * 4);
    int* cnt_ee = (int*)alloc((size_t)cEE * 4);
    int* S_ee   = (int*)alloc((size_t)(cEE + 1) * 4);
    int* cnt_et = (int*)alloc((size_t)cET * 4);
    int* S_et   = (int*)alloc((size_t)(cET + 1) * 4);
    int* cnt_te = (int*)alloc((size_t)cTE * 4);
    int* S_te   = (int*)alloc((size_t)(cTE + 1) * 4);
    int* bsum_ee = (int*)alloc(((size_t)(cEE + 1023) / 1024 + 1) * 4);
    int* bsum_et = (int*)alloc(((size_t)(cET + 1023) / 1024 + 1) * 4);
    int* bsum_te = (int*)alloc(((size_t)(cTE + 1023) / 1024 + 1) * 4);
    // edge pair buffers alias m_* (disjoint lifetime: CSR build ends before first agg)
    int2* eb_ee = (int2*)m_ee;   // EE*8 = 8MB  <= NE*D*2 = 25.6MB
    int2* eb_et = (int2*)m_te;   // ET*8 = 4MB  <= 25.6MB
    int2* eb_te = (int2*)m_et;   // TE*8 = 4MB  <= NT*D*2 = 5.1MB
    (void)ws_size; (void)n_in; (void)out_size;

    // ---- front: gather + hist + weight/bias prep + bounds + zero pooled5 (1 launch) -
    const int nGather = ((NE + NT) * 32 + 255) / 256;
    const int nblkH = nblkEE + nblkET + nblkTE;
    front_all<<<nGather + nblkH + 120 + 2 + 1 + 40, 256, 0, stream>>>(
        emb_event, event_ids, x_event, NE, emb_trace, trace_ids, x_trace, NT,
        event_batch, trace_batch, boundsE, boundsT,
        e2e_dst, EE, nbkEE, nblkEE, cnt_ee,
        e2t_dst, ET, nbkET, nblkET, cnt_et,
        t2e_dst, TE, nbkTE, nblkTE, cnt_te,
        Wl, Wr, bl, wbuf, bbuf, pooled5, nGather);

    // ---- CSR build: scan -> LDS-cursor scatter -> per-bucket CSR finalize ----
    const int nb1 = (cEE + 1023) >> 10, nb2 = (cET + 1023) >> 10, nb3 = (cTE + 1023) >> 10;
    scan_p1_all<<<nb1 + nb2 + nb3, 256, 0, stream>>>(
        cnt_ee, S_ee, bsum_ee, cEE, cnt_et, S_et, bsum_et, cET, cnt_te, S_te, bsum_te, cTE);
    scan_p23_all<<<((cEE + 255) >> 8) + ((cET + 255) >> 8) + ((cTE + 255) >> 8), 256, 0, stream>>>(
        S_ee, bsum_ee, cEE, S_et, bsum_et, cET, S_te, bsum_te, cTE);
    bkt_scatter_all<<<nblkEE + nblkET + nblkTE, 256, 0, stream>>>(
        e2e_src, e2e_dst, EE, nbkEE, nblkEE, S_ee, eb_ee,
        e2t_src, e2t_dst, ET, nbkET, nblkET, S_et, eb_et,
        t2e_src, t2e_dst, TE, nbkTE, nblkTE, S_te, eb_te);
    csr_build_all<<<nbkEE + nbkET + nbkTE, 256, 0, stream>>>(
        eb_ee, S_ee, nbkEE, nblkEE, NE, off_ee, adj_ee,
        eb_et, S_et, nbkET, nblkET, NT, off_et, adj_et,
        eb_te, S_te, nbkTE, nblkTE, NE, off_te, adj_te);

    // ---- layers 1..2: agg + MFMA GEMM; layer 3: agg (+root-pool blocks) only ----
    const int qE = (NE + 3) >> 2, qT = (NT + 3) >> 2;
    const int aggBlocks = (2 * qE + qT + 3) / 4;
    const int bE = (NE + 63) / 64, bT = (NT + 63) / 64;
    for (int l = 0; l < NLAY; ++l) {
        int extra = (l == NLAY - 1) ? 2 * NB * PSPLIT : 0;
        agg_all<<<aggBlocks + extra, 256, 0, stream>>>(x_event, x_trace,
                                                       off_ee, adj_ee, off_te, adj_te, off_et, adj_et,
                                                       m_ee, m_te, m_et, NE, NT, aggBlocks,
                                                       boundsE, boundsT, pooled5);
        if (l < NLAY - 1) {
            const bf16* wl_ev = wbuf + (size_t)l * 10 * D * D;
            const bf16* wl_tr = wl_ev + (size_t)6 * D * D;
            const float* be = bbuf + (size_t)l * 2 * D;
            const float* bt = be + D;
            gemm_all<<<bE + bT, 256, 0, stream>>>(m_ee, m_te, x_event, wl_ev, be, nx_event, NE, bE,
                                                  m_et, x_trace, wl_tr, bt, nx_trace, NT);
            bf16* t;
            t = x_event; x_event = nx_event; nx_event = t;
            t = x_trace; x_trace = nx_trace; nx_trace = t;
        }
    }

    // ---- layer-3 pool-before-GEMM: pool the 3 m-matrices, then fp32 tail ----
    pool_m_all<<<3 * NB * PSPLIT, 256, 0, stream>>>(m_ee, m_te, m_et,
                                                    boundsE, boundsT, pooled5);
    tail_kernel<<<NB, D, 0, stream>>>(pooled5, boundsE, boundsT, Wl, Wr, bl,
                                      W1, b1, W2, b2, (float*)d_out);
}